// Round 20
// baseline (2000.264 us; speedup 1.0000x reference)
//
#include <hip/hip_runtime.h>

typedef unsigned short u16;
typedef __attribute__((ext_vector_type(8))) short short8;
typedef __attribute__((ext_vector_type(4))) float f32x4;

#define B_ROWS 32768
#define T_STEPS 7
#define ENC_INd 60
#define DEC_INd 36
#define UNITS 356
#define KP_LSTM 448   /* [x:0..63][h:64..447] */
#define H_OFF 64
#define HID 768
#define OUTN 168
#define OUTNP 256
#define KMAP 2688     /* 7*384 */
#define HALF_E 44040192ull   /* 16384*2688 u16 elements per row-half of fbuf */
#define WLSTM_E 688128       /* 24 g-groups * 14 kk * 4 gates * 512 */
#define CG_BLK 6144          /* f32x4 per block: 6 passes * 4 mf * 256 threads */

__device__ __forceinline__ u16 f2b(float f) {
  unsigned u = __builtin_bit_cast(unsigned, f);
  u += 0x7fffu + ((u >> 16) & 1u);
  return (u16)(u >> 16);
}
__device__ __forceinline__ float sigm(float x) { return 1.0f / (1.0f + __expf(-x)); }
__device__ __forceinline__ float tanhfast(float x) { return 2.0f / (1.0f + __expf(-2.0f * x)) - 1.0f; }

__device__ __forceinline__ void stage16(const u16* g, u16* l) {
  __builtin_amdgcn_global_load_lds((const __attribute__((address_space(1))) void*)g,
                                   (__attribute__((address_space(3))) void*)l, 16, 0, 0);
}

__global__ void fill_sentinel(float* __restrict__ out, int n, float v) {
  int i = blockIdx.x * 256 + threadIdx.x;
  int stride = gridDim.x * 256;
  for (; i < n; i += stride) out[i] = v;
}

// ---------------- weight prep ----------------
// Fragment-major LSTM weights: WT[(g*14+kk)*2048 + nf*512 + lane*8 + e],
// g = 64-col group 0..23, unit u = g*16 + (lane&15), gate = nf,
// k = kk*32 + (lane>>4)*8 + e.  k: [0,in_dim) input kernel; [64,420) recurrent; else 0.
__global__ void prep_lstm_w(const float* __restrict__ Km, const float* __restrict__ Rm,
                            const float* __restrict__ bias, int in_dim,
                            u16* __restrict__ WT, float* __restrict__ bias_r)
{
  int idx = blockIdx.x * 256 + threadIdx.x;
  if (idx >= WLSTM_E) return;
  int e    = idx & 7;
  int lane = (idx >> 3) & 63;
  int nf   = (idx >> 9) & 3;
  int t1   = idx >> 11;          // g*14 + kk
  int kk   = t1 % 14;
  int g    = t1 / 14;
  int u = g * 16 + (lane & 15);
  int k = kk * 32 + ((lane >> 4) << 3) + e;
  float v = 0.f;
  if (u < UNITS) {
    int oc = nf * UNITS + u;
    if (k < in_dim) v = Km[(size_t)k * 1424 + oc];
    else if (k >= H_OFF && k < H_OFF + UNITS) v = Rm[(size_t)(k - H_OFF) * 1424 + oc];
    if (k == 0) bias_r[(u << 2) + nf] = bias[oc];
  } else if (k == 0) bias_r[(u << 2) + nf] = 0.f;
  WT[idx] = f2b(v);
}

// map weights: WT_map[n][k], k = t*384 + kk ; = W_map[t*356+kk][n] for kk<356 else 0
__global__ void prep_map_w(const float* __restrict__ W, u16* __restrict__ WT)
{
  int idx = blockIdx.x * 256 + threadIdx.x;
  if (idx >= HID * KMAP) return;
  int n = idx / KMAP, k = idx - n * KMAP;
  int t = k / 384, kk = k - t * 384;
  float v = (kk < UNITS) ? W[(size_t)(t * UNITS + kk) * HID + n] : 0.f;
  WT[idx] = f2b(v);
}

// transpose W[korig][norig] -> WT[n][kp] bf16, zero-padded
__global__ void prep_mlp_w(const float* __restrict__ W, int korig, int norig, int kp,
                           u16* __restrict__ WT, int total)
{
  int idx = blockIdx.x * 256 + threadIdx.x;
  if (idx >= total) return;
  int n = idx / kp, k = idx - n * kp;
  float v = (k < korig && n < norig) ? W[(size_t)k * norig + n] : 0.f;
  WT[idx] = f2b(v);
}

// ---------------- persistent LSTM: 512 blocks x 256 threads, 64 rows/block ----------------
// Cross-round inference (r13 vs r17: 2x B-stream ~= 10% time) killed the L2-BW theory;
// the binder is exposed per-kk L2 latency (~200cyc vs 80cyc MFMA cover) locked in by the
// 128-VGPR cap on 512/1024-thr blocks. 256-thr blocks get cap 256 (r9-proven grant).
// Config: 4 waves = 4 ns-slots (1 wave/SIMD), wave = 64 rows x 64 cols (mf=4), 6 passes,
// 4-deep named B pipeline (statically rotated, fully unrolled kk) + c-prefetch: 320cyc
// MFMA cover >= L2 latency. Ledger: acc64 + B64 + cw16 + af8 + temps ~180 <= 256.
// A-dbuf (1 barrier/step), XOR-swizzled A, c in global scratch, NT fbuf stores.
__global__ __launch_bounds__(256)
void lstm_persistent(const float* __restrict__ xg, const float* __restrict__ mg,
                     const u16* __restrict__ WTe, const float* __restrict__ bre,
                     const u16* __restrict__ WTd, const float* __restrict__ brd,
                     u16* __restrict__ fbuf,
                     f32x4* __restrict__ cg0, f32x4* __restrict__ cg1, f32x4* __restrict__ cg2)
{
  __shared__ __align__(16) u16 A[2][64][KP_LSTM];

  const int tid = threadIdx.x;
  const int ns = tid >> 6;          // wave = N-slot 0..3
  const int lane = tid & 63;
  const int l15 = lane & 15, l4 = lane >> 4;
  const int blk = blockIdx.x;
  const int row0 = blk * 64;

  f32x4* cgb;                       // per-block c scratch (3-way aliased)
  if (blk < 224)      cgb = cg0 + (size_t)blk * CG_BLK;
  else if (blk < 480) cgb = cg1 + (size_t)(blk - 224) * CG_BLK;
  else                cgb = cg2 + (size_t)(blk - 480) * CG_BLK;

  // zero h+pad region (16B blocks 8..55) of BOTH A buffers: 2*64*48 = 6144 tasks
  {
    short8 z = {};
    for (int q = tid; q < 6144; q += 256) {
      int buf = q / 3072, rem = q - buf * 3072;
      int row = rem / 48, blkc = 8 + (rem - row * 48);
      *(short8*)&A[buf][row][blkc << 3] = z;
    }
  }

#pragma unroll 1
  for (int s = 0; s < 14; ++s) {
    const u16*  wt = (s < 7) ? WTe : WTd;
    const float* br = (s < 7) ? bre : brd;
    const float* src = (s < 7) ? xg : mg;
    const int in_dim = (s < 7) ? ENC_INd : DEC_INd;
    const int t = (s < 7) ? s : s - 7;
    const int par = s & 1;

    // x_s -> A[par].x (cols 0..63, zero-padded): 64 rows x 8 col-blocks, 2 per thread
    {
      const int row = tid >> 2;
      const float* sp = src + ((size_t)(row0 + row) * T_STEPS + t) * in_dim;
#pragma unroll
      for (int qq = 0; qq < 2; ++qq) {
        const int cb = ((tid & 3) << 1) + qq;
        const int cbs = cb ^ (row & 7);
        short8 vv;
#pragma unroll
        for (int j = 0; j < 8; ++j) {
          const int cc = (cb << 3) + j;
          float v = (cc < in_dim) ? sp[cc] : 0.f;
          vv[j] = (short)f2b(v);
        }
        *(short8*)&A[par][row][cbs << 3] = vv;
      }
    }
    __syncthreads();   // x + h(s-1) visible; all waves done reading A[par^1] (step s-1)

#pragma unroll 1
    for (int p = 0; p < 6; ++p) {
      const int g = p * 4 + ns;
      f32x4 acc[4][4] = {};
      const u16* bp = wt + ((size_t)g * 14) * 2048 + (lane << 3);

      // c prefetch: issue loads BEFORE the MFMA chain
      f32x4 cw0, cw1, cw2, cw3;
      if (s > 0) {
        const int cib = (p * 4) * 256 + tid;
        cw0 = cgb[cib];
        cw1 = cgb[cib + 256];
        cw2 = cgb[cib + 512];
        cw3 = cgb[cib + 768];
      } else {
        cw0 = f32x4{0.f, 0.f, 0.f, 0.f}; cw1 = cw0; cw2 = cw0; cw3 = cw0;
      }

      short8 b0[4], b1[4], b2[4], b3[4];
      auto LOADB = [&](short8* d, int kk) {
#pragma unroll
        for (int nf = 0; nf < 4; ++nf)
          d[nf] = *(const short8*)(bp + kk * 2048 + (nf << 9));
      };
      auto MSTEP = [&](int kk, short8* b) {
        const int cbA = (kk << 2) + l4;
        short8 af[4];
#pragma unroll
        for (int mf = 0; mf < 4; ++mf) {
          const int ra = (mf << 4) + l15;
          const int cbs = (cbA & 56) | ((cbA ^ ra) & 7);
          af[mf] = *(const short8*)&A[par][ra][cbs << 3];
        }
#pragma unroll
        for (int mf = 0; mf < 4; ++mf)
#pragma unroll
          for (int nf = 0; nf < 4; ++nf)
            acc[mf][nf] = __builtin_amdgcn_mfma_f32_16x16x32_bf16(af[mf], b[nf], acc[mf][nf], 0, 0, 0);
      };

      LOADB(b0, 0); LOADB(b1, 1); LOADB(b2, 2); LOADB(b3, 3);
#pragma unroll
      for (int kk = 0; kk < 14; ++kk) {
        short8* bc = ((kk & 3) == 0) ? b0 : ((kk & 3) == 1) ? b1 : ((kk & 3) == 2) ? b2 : b3;
        MSTEP(kk, bc);
        if (kk + 4 < 14) LOADB(bc, kk + 4);
      }

      // epilogue: gates -> c (regs, write-back), h -> A[par^1].h + fbuf (NT)
      const int u = (g << 4) + l15;
      const int ch = H_OFF + u, cbh = ch >> 3, cih = ch & 7;
      float bz[4];
#pragma unroll
      for (int nf = 0; nf < 4; ++nf) bz[nf] = br[(u << 2) + nf];
#pragma unroll
      for (int mf = 0; mf < 4; ++mf) {
        f32x4 cw = (mf == 0) ? cw0 : (mf == 1) ? cw1 : (mf == 2) ? cw2 : cw3;
#pragma unroll
        for (int r = 0; r < 4; ++r) {
          const int row = (mf << 4) + (l4 << 2) + r;
          float zi = acc[mf][0][r] + bz[0];
          float zf = acc[mf][1][r] + bz[1];
          float zg = acc[mf][2][r] + bz[2];
          float zo = acc[mf][3][r] + bz[3];
          float ig = sigm(zi), fg = sigm(zf);
          float gg = tanhfast(zg), og = sigm(zo);
          float cn = fg * cw[r] + ig * gg;
          cw[r] = cn;
          float hv = og * tanhfast(cn);
          u16 hb = f2b(hv);
          const int cbs = (cbh & 56) | ((cbh ^ row) & 7);
          A[par ^ 1][row][(cbs << 3) + cih] = hb;
          if (s >= 7) {
            const int grow = row0 + row;
            __builtin_nontemporal_store(hb,
              &fbuf[(size_t)(grow >> 14) * HALF_E
                    + ((size_t)(grow & 16383) * T_STEPS + t) * 384 + u]);
          }
        }
        cgb[(p * 4 + mf) * 256 + tid] = cw;
      }
    }
  }
}

// ---------------- generic GEMM: C = A @ WT^T with per-mode epilogue ----------------
// Staging via global_load_lds width-16 (m97 pattern): linear LDS dest, source column
// pre-XOR'd so the swizzled read layout is unchanged.
// MODE 3: outb = bf16(tanh(acc + bias))
// MODE 4: outf = acc + bias   (guard n < nreal)
// MODE 5: outb = bf16(relu(acc + bias))
template<int MODE>
__global__ __launch_bounds__(256)
void mlp_gemm(const u16* __restrict__ A, int lda, int kp,
              const u16* __restrict__ WT, const float* __restrict__ bias, int nreal,
              u16* __restrict__ outb, float* __restrict__ outf, int ldo)
{
  __shared__ __align__(16) u16 lds_a[128 * 64];
  __shared__ __align__(16) u16 lds_b[128 * 64];
  const int tid = threadIdx.x;
  const int wid = tid >> 6, lane = tid & 63;
  const int wm = (wid >> 1) << 6, wn = (wid & 1) << 6;
  const int l15 = lane & 15, l4 = lane >> 4;
  const size_t abase = (size_t)blockIdx.x * 128 * lda;
  const size_t bbase = (size_t)blockIdx.y * 128 * kp;

  f32x4 acc[4][4] = {};

  for (int kt = 0; kt < kp; kt += 64) {
#pragma unroll
    for (int q = 0; q < 4; ++q) {
      const int u = q * 256 + tid;
      const int r = u >> 3, cb = u & 7;
      const int cs = kt + ((cb ^ (r & 7)) << 3);
      u16* da = &lds_a[(q * 256 + (wid << 6)) * 8];
      u16* db = &lds_b[(q * 256 + (wid << 6)) * 8];
      stage16(A + abase + (size_t)r * lda + cs, da);
      stage16(WT + bbase + (size_t)r * kp + cs, db);
    }
    __syncthreads();
#pragma unroll
    for (int kk = 0; kk < 2; ++kk) {
      short8 af[4], bfr[4];
#pragma unroll
      for (int mf = 0; mf < 4; ++mf) {
        int ra = wm + (mf << 4) + l15;
        int cb = (kk << 2) + l4;
        af[mf] = *(const short8*)&lds_a[(ra << 6) + ((cb ^ (ra & 7)) << 3)];
      }
#pragma unroll
      for (int nf = 0; nf < 4; ++nf) {
        int rb = wn + (nf << 4) + l15;
        int cb = (kk << 2) + l4;
        bfr[nf] = *(const short8*)&lds_b[(rb << 6) + ((cb ^ (rb & 7)) << 3)];
      }
#pragma unroll
      for (int mf = 0; mf < 4; ++mf)
#pragma unroll
        for (int nf = 0; nf < 4; ++nf)
          acc[mf][nf] = __builtin_amdgcn_mfma_f32_16x16x32_bf16(af[mf], bfr[nf], acc[mf][nf], 0, 0, 0);
    }
    __syncthreads();
  }

#pragma unroll
  for (int mf = 0; mf < 4; ++mf) {
    int rowb = blockIdx.x * 128 + wm + (mf << 4) + (l4 << 2);
#pragma unroll
    for (int r = 0; r < 4; ++r) {
      int row = rowb + r;
#pragma unroll
      for (int nf = 0; nf < 4; ++nf) {
        int n = blockIdx.y * 128 + wn + (nf << 4) + l15;
        float v = acc[mf][nf][r];
        size_t oi = (size_t)row * ldo + n;
        if (MODE == 3) {
          outb[oi] = f2b(tanhfast(v + bias[n]));
        } else if (MODE == 5) {
          outb[oi] = f2b(fmaxf(v + bias[n], 0.f));
        } else {
          if (n < nreal) outf[oi] = v + bias[n];
        }
      }
    }
  }
}

extern "C" void kernel_launch(void* const* d_in, const int* in_sizes, int n_in,
                              void* d_out, int out_size, void* d_ws, size_t ws_size,
                              hipStream_t stream)
{
  const float* x    = (const float*)d_in[0];
  const float* m    = (const float*)d_in[1];
  const float* ek   = (const float*)d_in[2];
  const float* erk  = (const float*)d_in[3];
  const float* eb   = (const float*)d_in[4];
  const float* dk   = (const float*)d_in[5];
  const float* drk  = (const float*)d_in[6];
  const float* dbi  = (const float*)d_in[7];
  const float* wmap = (const float*)d_in[8];
  const float* bmap = (const float*)d_in[9];
  const float* wd1  = (const float*)d_in[10];
  const float* bd1  = (const float*)d_in[11];
  const float* wd2  = (const float*)d_in[12];
  const float* bd2  = (const float*)d_in[13];
  const float* wout = (const float*)d_in[14];
  const float* bout = (const float*)d_in[15];

  char* ws = (char*)d_ws;
  size_t off = 0;
  auto alloc = [&](size_t bytes) { char* p = ws + off; off += (bytes + 255) & ~(size_t)255; return p; };

  u16*   WT_enc  = (u16*)  alloc((size_t)WLSTM_E * 2);          // 1.38 MB (fragment-major)
  u16*   WT_dec  = (u16*)  alloc((size_t)WLSTM_E * 2);          // 1.38 MB
  float* b_enc_r = (float*)alloc((size_t)384 * 4 * 4);          // [u][gate]
  float* b_dec_r = (float*)alloc((size_t)384 * 4 * 4);
  u16*   WT_map  = (u16*)  alloc((size_t)HID * KMAP * 2);       // 4.13 MB
  u16*   WT_d1   = (u16*)  alloc((size_t)HID * HID * 2);
  u16*   WT_d2   = (u16*)  alloc((size_t)HID * HID * 2);
  u16*   WT_out  = (u16*)  alloc((size_t)OUTNP * HID * 2);
  u16*   m1_h1   = (u16*)  alloc((size_t)16384 * HID * 2);      // 25.2 MB (also cg scratch during LSTM)
  u16*   fbuf    = (u16*)  alloc((size_t)2 * HALF_E * 2);       // 176.2 MB: [half][16384][7][384]
  f32x4* cg2     = (f32x4*)alloc((size_t)32 * CG_BLK * 16);     // 3.1 MB: c scratch for blocks 480..511
  const size_t NEED = off;                                      // ~214.2 MB (proven fits)

  if (ws_size < NEED) {
    fill_sentinel<<<256, 256, 0, stream>>>((float*)d_out, out_size, (float)(ws_size >> 20));
    return;
  }

  // c scratch aliasing during LSTM (all dead until after LSTM):
  f32x4* cg0 = (f32x4*)d_out;   // 22.0 MB = exactly 224 blocks * 98304 B
  f32x4* cg1 = (f32x4*)m1_h1;   // 25.2 MB -> 256 blocks

  // aliasing over dead fbuf halves (all stream-ordered):
  u16* fb_h0 = fbuf;
  u16* fb_h1 = fbuf + HALF_E;
  u16* m1_h0 = fb_h1;                    // written after fb_h1 consumed
  u16* m2_h0 = fb_h0;                    // written after both map GEMMs
  u16* m2_h1 = fb_h0 + (size_t)16384 * HID;
  u16* m3_h0 = fb_h1;                    // m1_h0 dead after d1(h0)
  u16* m3_h1 = m1_h1;                    // m1_h1 dead after d1(h1)

  // ---- weight prep ----
  prep_lstm_w<<<(WLSTM_E + 255) / 256, 256, 0, stream>>>(ek, erk, eb, ENC_INd, WT_enc, b_enc_r);
  prep_lstm_w<<<(WLSTM_E + 255) / 256, 256, 0, stream>>>(dk, drk, dbi, DEC_INd, WT_dec, b_dec_r);
  prep_map_w<<<((HID * KMAP) + 255) / 256, 256, 0, stream>>>(wmap, WT_map);
  prep_mlp_w<<<((HID * HID) + 255) / 256, 256, 0, stream>>>(wd1, HID, HID, HID, WT_d1, HID * HID);
  prep_mlp_w<<<((HID * HID) + 255) / 256, 256, 0, stream>>>(wd2, HID, HID, HID, WT_d2, HID * HID);
  prep_mlp_w<<<((OUTNP * HID) + 255) / 256, 256, 0, stream>>>(wout, HID, OUTN, HID, WT_out, OUTNP * HID);

  // ---- all 14 LSTM steps in one persistent kernel ----
  lstm_persistent<<<512, 256, 0, stream>>>(x, m, WT_enc, b_enc_r, WT_dec, b_dec_r, fbuf,
                                           cg0, cg1, cg2);

  // ---- map GEMM (K=2688), per row-half for aliasing ----
  mlp_gemm<5><<<dim3(128, 6), 256, 0, stream>>>(fb_h1, KMAP, KMAP, WT_map, bmap, HID, m1_h1, nullptr, HID);
  mlp_gemm<5><<<dim3(128, 6), 256, 0, stream>>>(fb_h0, KMAP, KMAP, WT_map, bmap, HID, m1_h0, nullptr, HID);
  // ---- deep MLP ----
  mlp_gemm<3><<<dim3(128, 6), 256, 0, stream>>>(m1_h0, HID, HID, WT_d1, bd1, HID, m2_h0, nullptr, HID);
  mlp_gemm<3><<<dim3(128, 6), 256, 0, stream>>>(m1_h1, HID, HID, WT_d1, bd1, HID, m2_h1, nullptr, HID);
  mlp_gemm<3><<<dim3(128, 6), 256, 0, stream>>>(m2_h0, HID, HID, WT_d2, bd2, HID, m3_h0, nullptr, HID);
  mlp_gemm<3><<<dim3(128, 6), 256, 0, stream>>>(m2_h1, HID, HID, WT_d2, bd2, HID, m3_h1, nullptr, HID);
  // ---- output ----
  mlp_gemm<4><<<dim3(128, 2), 256, 0, stream>>>(m3_h0, HID, HID, WT_out, bout, OUTN,
                                                nullptr, (float*)d_out, OUTN);
  mlp_gemm<4><<<dim3(128, 2), 256, 0, stream>>>(m3_h1, HID, HID, WT_out, bout, OUTN,
                                                nullptr, (float*)d_out + (size_t)16384 * OUTN, OUTN);
}

// Round 21
// 1446.560 us; speedup vs baseline: 1.3828x; 1.3828x over previous
//
#include <hip/hip_runtime.h>

typedef unsigned short u16;
typedef __attribute__((ext_vector_type(8))) short short8;
typedef __attribute__((ext_vector_type(4))) float f32x4;

#define B_ROWS 32768
#define T_STEPS 7
#define ENC_INd 60
#define DEC_INd 36
#define UNITS 356
#define KP_LSTM 448   /* logical K: [x:0..63][h:64..447] */
#define ASTR 456      /* A row stride (u16): 912B; 228 dwords % 32 == 4 -> uniform banks, no XOR needed */
#define H_OFF 64
#define HID 768
#define OUTN 168
#define OUTNP 256
#define KMAP 2688     /* 7*384 */
#define HALF_E 44040192ull   /* 16384*2688 u16 elements per row-half of fbuf */
#define WLSTM_E 688128       /* 24 g-groups * 14 kk * 4 gates * 512 */
#define CG_BLK 6144          /* f32x4 per block: 3 passes * 4 mf * 512 threads */

__device__ __forceinline__ u16 f2b(float f) {
  unsigned u = __builtin_bit_cast(unsigned, f);
  u += 0x7fffu + ((u >> 16) & 1u);
  return (u16)(u >> 16);
}
__device__ __forceinline__ float sigm(float x) { return 1.0f / (1.0f + __expf(-x)); }
__device__ __forceinline__ float tanhfast(float x) { return 2.0f / (1.0f + __expf(-2.0f * x)) - 1.0f; }

__device__ __forceinline__ void stage16(const u16* g, u16* l) {
  __builtin_amdgcn_global_load_lds((const __attribute__((address_space(1))) void*)g,
                                   (__attribute__((address_space(3))) void*)l, 16, 0, 0);
}

__global__ void fill_sentinel(float* __restrict__ out, int n, float v) {
  int i = blockIdx.x * 256 + threadIdx.x;
  int stride = gridDim.x * 256;
  for (; i < n; i += stride) out[i] = v;
}

// ---------------- weight prep ----------------
// Fragment-major LSTM weights: WT[(g*14+kk)*2048 + nf*512 + lane*8 + e],
// g = 64-col group 0..23, unit u = g*16 + (lane&15), gate = nf,
// k = kk*32 + (lane>>4)*8 + e.  k: [0,in_dim) input kernel; [64,420) recurrent; else 0.
__global__ void prep_lstm_w(const float* __restrict__ Km, const float* __restrict__ Rm,
                            const float* __restrict__ bias, int in_dim,
                            u16* __restrict__ WT, float* __restrict__ bias_r)
{
  int idx = blockIdx.x * 256 + threadIdx.x;
  if (idx >= WLSTM_E) return;
  int e    = idx & 7;
  int lane = (idx >> 3) & 63;
  int nf   = (idx >> 9) & 3;
  int t1   = idx >> 11;          // g*14 + kk
  int kk   = t1 % 14;
  int g    = t1 / 14;
  int u = g * 16 + (lane & 15);
  int k = kk * 32 + ((lane >> 4) << 3) + e;
  float v = 0.f;
  if (u < UNITS) {
    int oc = nf * UNITS + u;
    if (k < in_dim) v = Km[(size_t)k * 1424 + oc];
    else if (k >= H_OFF && k < H_OFF + UNITS) v = Rm[(size_t)(k - H_OFF) * 1424 + oc];
    if (k == 0) bias_r[(u << 2) + nf] = bias[oc];
  } else if (k == 0) bias_r[(u << 2) + nf] = 0.f;
  WT[idx] = f2b(v);
}

// map weights: WT_map[n][k], k = t*384 + kk ; = W_map[t*356+kk][n] for kk<356 else 0
__global__ void prep_map_w(const float* __restrict__ W, u16* __restrict__ WT)
{
  int idx = blockIdx.x * 256 + threadIdx.x;
  if (idx >= HID * KMAP) return;
  int n = idx / KMAP, k = idx - n * KMAP;
  int t = k / 384, kk = k - t * 384;
  float v = (kk < UNITS) ? W[(size_t)(t * UNITS + kk) * HID + n] : 0.f;
  WT[idx] = f2b(v);
}

// transpose W[korig][norig] -> WT[n][kp] bf16, zero-padded
__global__ void prep_mlp_w(const float* __restrict__ W, int korig, int norig, int kp,
                           u16* __restrict__ WT, int total)
{
  int idx = blockIdx.x * 256 + threadIdx.x;
  if (idx >= total) return;
  int n = idx / kp, k = idx - n * kp;
  float v = (k < korig && n < norig) ? W[(size_t)k * norig + n] : 0.f;
  WT[idx] = f2b(v);
}

// ---------------- persistent LSTM: 512 blocks x 512 threads, 64 rows/block ----------------
// r17 (best: 1112us) + VALU diet: r17's counters show VALU is the dominant pipe
// (56% busy = 620us) while MFMA sits at its 278us floor. Largest kk-loop VALU consumer =
// XOR-swizzle address math (~670 ops/thread/step). Fix: A rows padded to 456 u16 (912B;
// 228 dwords %32==4) -> 16-row x 4-l4 b128 column reads distribute exactly 8 dword-touches
// per bank (uniform minimum, r19-measured 0 conflicts) WITHOUT any swizzle. A-fragment
// addressing = 4 precomputed per-lane byte bases + kk*64B immediates (zero per-kk VALU);
// h/x writes linear. Everything else (c-prefetch, A-dbuf, NT fbuf, 8 waves x 3 passes,
// tail) identical to r17.
__global__ __launch_bounds__(512)
void lstm_persistent(const float* __restrict__ xg, const float* __restrict__ mg,
                     const u16* __restrict__ WTe, const float* __restrict__ bre,
                     const u16* __restrict__ WTd, const float* __restrict__ brd,
                     u16* __restrict__ fbuf,
                     f32x4* __restrict__ cg0, f32x4* __restrict__ cg1, f32x4* __restrict__ cg2)
{
  __shared__ __align__(16) u16 A[2][64][ASTR];   // 116,736 B

  const int tid = threadIdx.x;
  const int ns = tid >> 6;          // wave = N-slot 0..7
  const int lane = tid & 63;
  const int l15 = lane & 15, l4 = lane >> 4;
  const int blk = blockIdx.x;
  const int row0 = blk * 64;

  f32x4* cgb;                       // per-block c scratch (3-way aliased)
  if (blk < 224)      cgb = cg0 + (size_t)blk * CG_BLK;
  else if (blk < 480) cgb = cg1 + (size_t)(blk - 224) * CG_BLK;
  else                cgb = cg2 + (size_t)(blk - 480) * CG_BLK;

  // per-lane A byte bases (mf = 0..3): row (mf*16 + l15), col l4*16B; + kk*64B at use
  int aoff[4];
#pragma unroll
  for (int mf = 0; mf < 4; ++mf)
    aoff[mf] = (((mf << 4) + l15) * ASTR + (l4 << 3)) * 2;

  // zero h+pad region (16B blocks 8..56 = cols 64..455) of BOTH A buffers: 2*64*49 tasks
  {
    short8 z = {};
    for (int q = tid; q < 6272; q += 512) {
      int buf = q / 3136, rem = q - buf * 3136;
      int row = rem / 49, blkc = 8 + (rem - row * 49);
      *(short8*)&A[buf][row][blkc << 3] = z;
    }
  }

#pragma unroll 1
  for (int s = 0; s < 14; ++s) {
    const u16*  wt = (s < 7) ? WTe : WTd;
    const float* br = (s < 7) ? bre : brd;
    const float* src = (s < 7) ? xg : mg;
    const int in_dim = (s < 7) ? ENC_INd : DEC_INd;
    const int t = (s < 7) ? s : s - 7;
    const int par = s & 1;

    // x_s -> A[par].x (cols 0..63, zero-padded): 64 rows x 8 col-blocks, linear
    {
      const int row = tid >> 3, cb = tid & 7;
      const float* sp = src + ((size_t)(row0 + row) * T_STEPS + t) * in_dim;
      short8 vv;
#pragma unroll
      for (int j = 0; j < 8; ++j) {
        const int cc = (cb << 3) + j;
        float v = (cc < in_dim) ? sp[cc] : 0.f;
        vv[j] = (short)f2b(v);
      }
      *(short8*)&A[par][row][cb << 3] = vv;
    }
    __syncthreads();   // x + h(s-1) visible; all waves done reading A[par^1] (step s-1)

    const char* Ab = (const char*)&A[par][0][0];

#pragma unroll 1
    for (int p = 0; p < 3; ++p) {
      const int g = p * 8 + ns;
      f32x4 acc[4][4] = {};
      const u16* bp = wt + ((size_t)g * 14) * 2048 + (lane << 3);

      // c prefetch: issue HBM loads BEFORE the MFMA chain (epilogue reads registers)
      f32x4 cw0, cw1, cw2, cw3;
      if (s > 0) {
        const int cib = (p * 4) * 512 + tid;
        cw0 = cgb[cib];
        cw1 = cgb[cib + 512];
        cw2 = cgb[cib + 1024];
        cw3 = cgb[cib + 1536];
      } else {
        cw0 = f32x4{0.f, 0.f, 0.f, 0.f}; cw1 = cw0; cw2 = cw0; cw3 = cw0;
      }

#pragma unroll 1
      for (int kk = 0; kk < 14; ++kk) {
        short8 bf[4];
#pragma unroll
        for (int nf = 0; nf < 4; ++nf)
          bf[nf] = *(const short8*)(bp + kk * 2048 + (nf << 9));
        {
          short8 af0[2];
          af0[0] = *(const short8*)(Ab + aoff[0] + (kk << 6));
          af0[1] = *(const short8*)(Ab + aoff[1] + (kk << 6));
#pragma unroll
          for (int mf = 0; mf < 2; ++mf)
#pragma unroll
            for (int nf = 0; nf < 4; ++nf)
              acc[mf][nf] = __builtin_amdgcn_mfma_f32_16x16x32_bf16(af0[mf], bf[nf], acc[mf][nf], 0, 0, 0);
        }
        {
          short8 af1[2];
          af1[0] = *(const short8*)(Ab + aoff[2] + (kk << 6));
          af1[1] = *(const short8*)(Ab + aoff[3] + (kk << 6));
#pragma unroll
          for (int mf = 0; mf < 2; ++mf)
#pragma unroll
            for (int nf = 0; nf < 4; ++nf)
              acc[mf + 2][nf] = __builtin_amdgcn_mfma_f32_16x16x32_bf16(af1[mf], bf[nf], acc[mf + 2][nf], 0, 0, 0);
        }
      }

      // epilogue: gates -> c (regs, write-back), h -> A[par^1].h (linear) + fbuf (NT)
      const int u = (g << 4) + l15;
      const int chc = H_OFF + u;
      float bz[4];
#pragma unroll
      for (int nf = 0; nf < 4; ++nf) bz[nf] = br[(u << 2) + nf];
#pragma unroll
      for (int mf = 0; mf < 4; ++mf) {
        f32x4 cw = (mf == 0) ? cw0 : (mf == 1) ? cw1 : (mf == 2) ? cw2 : cw3;
#pragma unroll
        for (int r = 0; r < 4; ++r) {
          const int row = (mf << 4) + (l4 << 2) + r;
          float zi = acc[mf][0][r] + bz[0];
          float zf = acc[mf][1][r] + bz[1];
          float zg = acc[mf][2][r] + bz[2];
          float zo = acc[mf][3][r] + bz[3];
          float ig = sigm(zi), fg = sigm(zf);
          float gg = tanhfast(zg), og = sigm(zo);
          float cn = fg * cw[r] + ig * gg;
          cw[r] = cn;
          float hv = og * tanhfast(cn);
          u16 hb = f2b(hv);
          A[par ^ 1][row][chc] = hb;
          if (s >= 7) {
            const int grow = row0 + row;
            __builtin_nontemporal_store(hb,
              &fbuf[(size_t)(grow >> 14) * HALF_E
                    + ((size_t)(grow & 16383) * T_STEPS + t) * 384 + u]);
          }
        }
        cgb[(p * 4 + mf) * 512 + tid] = cw;
      }
    }
  }
}

// ---------------- generic GEMM: C = A @ WT^T with per-mode epilogue ----------------
// Staging via global_load_lds width-16 (m97 pattern): linear LDS dest, source column
// pre-XOR'd so the swizzled read layout is unchanged.
// MODE 3: outb = bf16(tanh(acc + bias))
// MODE 4: outf = acc + bias   (guard n < nreal)
// MODE 5: outb = bf16(relu(acc + bias))
template<int MODE>
__global__ __launch_bounds__(256)
void mlp_gemm(const u16* __restrict__ A, int lda, int kp,
              const u16* __restrict__ WT, const float* __restrict__ bias, int nreal,
              u16* __restrict__ outb, float* __restrict__ outf, int ldo)
{
  __shared__ __align__(16) u16 lds_a[128 * 64];
  __shared__ __align__(16) u16 lds_b[128 * 64];
  const int tid = threadIdx.x;
  const int wid = tid >> 6, lane = tid & 63;
  const int wm = (wid >> 1) << 6, wn = (wid & 1) << 6;
  const int l15 = lane & 15, l4 = lane >> 4;
  const size_t abase = (size_t)blockIdx.x * 128 * lda;
  const size_t bbase = (size_t)blockIdx.y * 128 * kp;

  f32x4 acc[4][4] = {};

  for (int kt = 0; kt < kp; kt += 64) {
#pragma unroll
    for (int q = 0; q < 4; ++q) {
      const int u = q * 256 + tid;
      const int r = u >> 3, cb = u & 7;
      const int cs = kt + ((cb ^ (r & 7)) << 3);
      u16* da = &lds_a[(q * 256 + (wid << 6)) * 8];
      u16* db = &lds_b[(q * 256 + (wid << 6)) * 8];
      stage16(A + abase + (size_t)r * lda + cs, da);
      stage16(WT + bbase + (size_t)r * kp + cs, db);
    }
    __syncthreads();
#pragma unroll
    for (int kk = 0; kk < 2; ++kk) {
      short8 af[4], bfr[4];
#pragma unroll
      for (int mf = 0; mf < 4; ++mf) {
        int ra = wm + (mf << 4) + l15;
        int cb = (kk << 2) + l4;
        af[mf] = *(const short8*)&lds_a[(ra << 6) + ((cb ^ (ra & 7)) << 3)];
      }
#pragma unroll
      for (int nf = 0; nf < 4; ++nf) {
        int rb = wn + (nf << 4) + l15;
        int cb = (kk << 2) + l4;
        bfr[nf] = *(const short8*)&lds_b[(rb << 6) + ((cb ^ (rb & 7)) << 3)];
      }
#pragma unroll
      for (int mf = 0; mf < 4; ++mf)
#pragma unroll
        for (int nf = 0; nf < 4; ++nf)
          acc[mf][nf] = __builtin_amdgcn_mfma_f32_16x16x32_bf16(af[mf], bfr[nf], acc[mf][nf], 0, 0, 0);
    }
    __syncthreads();
  }

#pragma unroll
  for (int mf = 0; mf < 4; ++mf) {
    int rowb = blockIdx.x * 128 + wm + (mf << 4) + (l4 << 2);
#pragma unroll
    for (int r = 0; r < 4; ++r) {
      int row = rowb + r;
#pragma unroll
      for (int nf = 0; nf < 4; ++nf) {
        int n = blockIdx.y * 128 + wn + (nf << 4) + l15;
        float v = acc[mf][nf][r];
        size_t oi = (size_t)row * ldo + n;
        if (MODE == 3) {
          outb[oi] = f2b(tanhfast(v + bias[n]));
        } else if (MODE == 5) {
          outb[oi] = f2b(fmaxf(v + bias[n], 0.f));
        } else {
          if (n < nreal) outf[oi] = v + bias[n];
        }
      }
    }
  }
}

extern "C" void kernel_launch(void* const* d_in, const int* in_sizes, int n_in,
                              void* d_out, int out_size, void* d_ws, size_t ws_size,
                              hipStream_t stream)
{
  const float* x    = (const float*)d_in[0];
  const float* m    = (const float*)d_in[1];
  const float* ek   = (const float*)d_in[2];
  const float* erk  = (const float*)d_in[3];
  const float* eb   = (const float*)d_in[4];
  const float* dk   = (const float*)d_in[5];
  const float* drk  = (const float*)d_in[6];
  const float* dbi  = (const float*)d_in[7];
  const float* wmap = (const float*)d_in[8];
  const float* bmap = (const float*)d_in[9];
  const float* wd1  = (const float*)d_in[10];
  const float* bd1  = (const float*)d_in[11];
  const float* wd2  = (const float*)d_in[12];
  const float* bd2  = (const float*)d_in[13];
  const float* wout = (const float*)d_in[14];
  const float* bout = (const float*)d_in[15];

  char* ws = (char*)d_ws;
  size_t off = 0;
  auto alloc = [&](size_t bytes) { char* p = ws + off; off += (bytes + 255) & ~(size_t)255; return p; };

  u16*   WT_enc  = (u16*)  alloc((size_t)WLSTM_E * 2);          // 1.38 MB (fragment-major)
  u16*   WT_dec  = (u16*)  alloc((size_t)WLSTM_E * 2);          // 1.38 MB
  float* b_enc_r = (float*)alloc((size_t)384 * 4 * 4);          // [u][gate]
  float* b_dec_r = (float*)alloc((size_t)384 * 4 * 4);
  u16*   WT_map  = (u16*)  alloc((size_t)HID * KMAP * 2);       // 4.13 MB
  u16*   WT_d1   = (u16*)  alloc((size_t)HID * HID * 2);
  u16*   WT_d2   = (u16*)  alloc((size_t)HID * HID * 2);
  u16*   WT_out  = (u16*)  alloc((size_t)OUTNP * HID * 2);
  u16*   m1_h1   = (u16*)  alloc((size_t)16384 * HID * 2);      // 25.2 MB (also cg scratch during LSTM)
  u16*   fbuf    = (u16*)  alloc((size_t)2 * HALF_E * 2);       // 176.2 MB: [half][16384][7][384]
  f32x4* cg2     = (f32x4*)alloc((size_t)32 * CG_BLK * 16);     // 3.1 MB: c scratch for blocks 480..511
  const size_t NEED = off;                                      // ~214.2 MB (proven fits)

  if (ws_size < NEED) {
    fill_sentinel<<<256, 256, 0, stream>>>((float*)d_out, out_size, (float)(ws_size >> 20));
    return;
  }

  // c scratch aliasing during LSTM (all dead until after LSTM):
  f32x4* cg0 = (f32x4*)d_out;   // 22.0 MB = exactly 224 blocks * 98304 B
  f32x4* cg1 = (f32x4*)m1_h1;   // 25.2 MB -> 256 blocks

  // aliasing over dead fbuf halves (all stream-ordered):
  u16* fb_h0 = fbuf;
  u16* fb_h1 = fbuf + HALF_E;
  u16* m1_h0 = fb_h1;                    // written after fb_h1 consumed
  u16* m2_h0 = fb_h0;                    // written after both map GEMMs
  u16* m2_h1 = fb_h0 + (size_t)16384 * HID;
  u16* m3_h0 = fb_h1;                    // m1_h0 dead after d1(h0)
  u16* m3_h1 = m1_h1;                    // m1_h1 dead after d1(h1)

  // ---- weight prep ----
  prep_lstm_w<<<(WLSTM_E + 255) / 256, 256, 0, stream>>>(ek, erk, eb, ENC_INd, WT_enc, b_enc_r);
  prep_lstm_w<<<(WLSTM_E + 255) / 256, 256, 0, stream>>>(dk, drk, dbi, DEC_INd, WT_dec, b_dec_r);
  prep_map_w<<<((HID * KMAP) + 255) / 256, 256, 0, stream>>>(wmap, WT_map);
  prep_mlp_w<<<((HID * HID) + 255) / 256, 256, 0, stream>>>(wd1, HID, HID, HID, WT_d1, HID * HID);
  prep_mlp_w<<<((HID * HID) + 255) / 256, 256, 0, stream>>>(wd2, HID, HID, HID, WT_d2, HID * HID);
  prep_mlp_w<<<((OUTNP * HID) + 255) / 256, 256, 0, stream>>>(wout, HID, OUTN, HID, WT_out, OUTNP * HID);

  // ---- all 14 LSTM steps in one persistent kernel ----
  lstm_persistent<<<512, 512, 0, stream>>>(x, m, WT_enc, b_enc_r, WT_dec, b_dec_r, fbuf,
                                           cg0, cg1, cg2);

  // ---- map GEMM (K=2688), per row-half for aliasing ----
  mlp_gemm<5><<<dim3(128, 6), 256, 0, stream>>>(fb_h1, KMAP, KMAP, WT_map, bmap, HID, m1_h1, nullptr, HID);
  mlp_gemm<5><<<dim3(128, 6), 256, 0, stream>>>(fb_h0, KMAP, KMAP, WT_map, bmap, HID, m1_h0, nullptr, HID);
  // ---- deep MLP ----
  mlp_gemm<3><<<dim3(128, 6), 256, 0, stream>>>(m1_h0, HID, HID, WT_d1, bd1, HID, m2_h0, nullptr, HID);
  mlp_gemm<3><<<dim3(128, 6), 256, 0, stream>>>(m1_h1, HID, HID, WT_d1, bd1, HID, m2_h1, nullptr, HID);
  mlp_gemm<3><<<dim3(128, 6), 256, 0, stream>>>(m2_h0, HID, HID, WT_d2, bd2, HID, m3_h0, nullptr, HID);
  mlp_gemm<3><<<dim3(128, 6), 256, 0, stream>>>(m2_h1, HID, HID, WT_d2, bd2, HID, m3_h1, nullptr, HID);
  // ---- output ----
  mlp_gemm<4><<<dim3(128, 2), 256, 0, stream>>>(m3_h0, HID, HID, WT_out, bout, OUTN,
                                                nullptr, (float*)d_out, OUTN);
  mlp_gemm<4><<<dim3(128, 2), 256, 0, stream>>>(m3_h1, HID, HID, WT_out, bout, OUTN,
                                                nullptr, (float*)d_out + (size_t)16384 * OUTN, OUTN);
}